// Round 5
// baseline (409.475 us; speedup 1.0000x reference)
//
#include <hip/hip_runtime.h>
#include <math.h>

#define B   32
#define T   50
#define N1  50001
#define D   128
#define KP  16
#define MP  50
#define HID 72
#define BT  (B*T)

typedef __attribute__((ext_vector_type(8))) short short8v;
typedef __attribute__((ext_vector_type(4))) float f32x4;

__device__ __forceinline__ unsigned short f2bf(float x) {
    unsigned u = __float_as_uint(x);
    u += 0x7fffu + ((u >> 16) & 1u);
    return (unsigned short)(u >> 16);
}

// ---------------- helpers ----------------
__device__ __forceinline__ float blockReduceSum128(float val, volatile float* sbuf) {
    // blockDim.x == 128 (2 waves of 64)
    for (int off = 32; off > 0; off >>= 1) val += __shfl_down(val, off, 64);
    __syncthreads();                       // protect sbuf from previous use
    if ((threadIdx.x & 63) == 0) sbuf[threadIdx.x >> 6] = val;
    __syncthreads();
    return sbuf[0] + sbuf[1];
}

// ---------------- 1. ProxySelection MLP per (b,t) ----------------
__global__ void k_proxy_x2(const int* __restrict__ session,
                           const float* __restrict__ I_emb,
                           const float* __restrict__ EP_emb,
                           const float* __restrict__ WP1,
                           const float* __restrict__ WP2,
                           float* __restrict__ X2) {
    int bt = blockIdx.x; int t = bt % T;
    int tid = threadIdx.x;                 // 128
    __shared__ __align__(16) float x[D];
    __shared__ float h[HID];
    int sid = session[bt];
    float val = 0.f;
    if (sid != 0) val = I_emb[(size_t)sid * D + tid] + EP_emb[(t + MP - T) * D + tid];
    x[tid] = val;
    __syncthreads();
    if (tid < HID) {
        float acc = 0.f;
        const float4* w4 = (const float4*)(WP1 + tid * D);
        const float4* x4 = (const float4*)x;
        #pragma unroll 8
        for (int k = 0; k < D / 4; ++k) {
            float4 w = w4[k]; float4 xv = x4[k];
            acc += xv.x * w.x + xv.y * w.y + xv.z * w.z + xv.w * w.w;
        }
        h[tid] = acc > 0.f ? acc : 0.1f * acc;   // leaky_relu 0.1
    }
    __syncthreads();
    if (tid < KP) {
        float acc = 0.f;
        const float* w = WP2 + tid * HID;
        for (int k = 0; k < HID; ++k) acc += h[k] * w[k];
        X2[bt * KP + tid] = acc;
    }
}

// ---------------- 2. softmax head: pi, p_s, v, orthogonal ----------------
__global__ void k_proxy_head(const float* __restrict__ X2,
                             const int* __restrict__ lengths,
                             const int* __restrict__ tau_i,
                             const float* __restrict__ P_emb,
                             const float* __restrict__ V,
                             float* __restrict__ ps_o,
                             float* __restrict__ v_o,
                             float* __restrict__ orth_o) {
    int b = blockIdx.x; int tid = threadIdx.x;   // 128
    __shared__ float pi[KP];
    __shared__ float vn[KP];
    __shared__ float sbuf[2];
    float tau = (float)tau_i[0];
    float lf = (float)lengths[b];
    if (tid < KP) {
        float s = 0.f;
        for (int t = 0; t < T; ++t) s += X2[(b * T + t) * KP + tid];
        pi[tid] = (s / lf) / tau;
    }
    if (tid < KP) {   // V row norms
        float s = 0.f;
        for (int d = 0; d < D; ++d) { float z = V[tid * D + d]; s += z * z; }
        vn[tid] = fmaxf(sqrtf(s), 1e-12f);
    }
    __syncthreads();
    if (tid == 0) {
        float m = pi[0];
        for (int k = 1; k < KP; ++k) m = fmaxf(m, pi[k]);
        float s = 0.f;
        for (int k = 0; k < KP; ++k) { float e = expf(pi[k] - m); pi[k] = e; s += e; }
        for (int k = 0; k < KP; ++k) pi[k] /= s;
    }
    __syncthreads();
    float p = 0.f, vt = 0.f;
    for (int k = 0; k < KP; ++k) {
        p  += pi[k] * P_emb[k * D + tid];
        vt += pi[k] * (V[k * D + tid] / vn[k]);
    }
    float vsq = blockReduceSum128(vt * vt, sbuf);
    float vv = vt / fmaxf(sqrtf(vsq), 1e-12f);
    float psq = blockReduceSum128(p * p, sbuf);
    float dvp = blockReduceSum128(vv * p, sbuf);
    ps_o[b * D + tid] = p;
    v_o[b * D + tid] = vv;
    if (tid == 0) orth_o[b] = fabsf(dvp) / sqrtf(psq);
}

// ---------------- 3. Xs, q, k, v ----------------
__global__ void k_xs_qkv(const int* __restrict__ session,
                         const int* __restrict__ lengths,
                         const float* __restrict__ I_emb,
                         const float* __restrict__ ES_emb,
                         const float* __restrict__ Wq,
                         const float* __restrict__ Wk,
                         const float* __restrict__ Wv,
                         float* __restrict__ xs_o, float* __restrict__ q_o,
                         float* __restrict__ k_o, float* __restrict__ v_o) {
    int bt = blockIdx.x; int b = bt / T; int t = bt % T;
    int tid = threadIdx.x;  // 128
    __shared__ __align__(16) float xs[D];
    int sid = session[bt];
    int es = t + 1 - (T - lengths[b]); if (es < 0) es = 0;
    float x = I_emb[(size_t)sid * D + tid] + ES_emb[es * D + tid];
    xs[tid] = x;
    __syncthreads();
    float aq = 0.f, ak = 0.f, av = 0.f;
    const float4* wq4 = (const float4*)(Wq + tid * D);
    const float4* wk4 = (const float4*)(Wk + tid * D);
    const float4* wv4 = (const float4*)(Wv + tid * D);
    const float4* x4  = (const float4*)xs;
    #pragma unroll 8
    for (int k = 0; k < D / 4; ++k) {
        float4 xv = x4[k];
        float4 a = wq4[k], bq = wk4[k], c = wv4[k];
        aq += xv.x * a.x + xv.y * a.y + xv.z * a.z + xv.w * a.w;
        ak += xv.x * bq.x + xv.y * bq.y + xv.z * bq.z + xv.w * bq.w;
        av += xv.x * c.x + xv.y * c.y + xv.z * c.z + xv.w * c.w;
    }
    xs_o[bt * D + tid] = x; q_o[bt * D + tid] = aq; k_o[bt * D + tid] = ak; v_o[bt * D + tid] = av;
}

// ---------------- 4. attention: scores + softmax + attn@vv ----------------
__global__ void k_attn(const int* __restrict__ session,
                       const float* __restrict__ q,
                       const float* __restrict__ kk,
                       const float* __restrict__ vv,
                       float* __restrict__ ho) {
    int bt = blockIdx.x; int b = bt / T; int t = bt % T;
    int tid = threadIdx.x;  // 128
    __shared__ __align__(16) float qs[D];
    __shared__ float attn[64];
    qs[tid] = q[bt * D + tid];
    __syncthreads();
    if (tid < T) {
        int s = tid;
        bool allowed = (s == 0) || ((s <= t) && (session[b * T + s] != 0));
        float sc = -1e9f;
        if (allowed) {
            float a = 0.f;
            const float4* kr = (const float4*)(kk + (size_t)(b * T + s) * D);
            const float4* q4 = (const float4*)qs;
            #pragma unroll 8
            for (int d = 0; d < D / 4; ++d) {
                float4 kv = kr[d]; float4 qv = q4[d];
                a += qv.x * kv.x + qv.y * kv.y + qv.z * kv.z + qv.w * kv.w;
            }
            sc = a * 0.088388347648318447f;  // 1/sqrt(128)
        }
        attn[s] = sc;
    }
    __syncthreads();
    if (tid < 64) {
        float vsc = (tid < T) ? attn[tid] : -1e30f;
        float m = vsc;
        for (int off = 32; off > 0; off >>= 1) m = fmaxf(m, __shfl_xor(m, off, 64));
        float e = (tid < T) ? expf(vsc - m) : 0.f;
        float ssum = e;
        for (int off = 32; off > 0; off >>= 1) ssum += __shfl_xor(ssum, off, 64);
        if (tid < T) attn[tid] = e / ssum;
    }
    __syncthreads();
    float acc = 0.f;
    for (int s = 0; s < T; ++s) acc += attn[s] * vv[(size_t)(b * T + s) * D + tid];
    ho[bt * D + tid] = acc;
}

// ---------------- 5. Wo + residual + LN1 ----------------
__global__ void k_post_attn(const int* __restrict__ session,
                            const float* __restrict__ ho,
                            const float* __restrict__ Wo,
                            const float* __restrict__ xs,
                            const float* __restrict__ g1, const float* __restrict__ b1,
                            float* __restrict__ h_o) {
    int bt = blockIdx.x; int tid = threadIdx.x;
    __shared__ __align__(16) float hr[D];
    __shared__ float sbuf[2];
    hr[tid] = ho[bt * D + tid];
    __syncthreads();
    float a = 0.f;
    const float4* w4 = (const float4*)(Wo + tid * D);
    const float4* h4 = (const float4*)hr;
    #pragma unroll 8
    for (int k = 0; k < D / 4; ++k) {
        float4 w = w4[k]; float4 hv = h4[k];
        a += hv.x * w.x + hv.y * w.y + hv.z * w.z + hv.w * w.w;
    }
    float x = a + xs[bt * D + tid];
    float mean = blockReduceSum128(x, sbuf) * (1.f / D);
    float dx = x - mean;
    float var = blockReduceSum128(dx * dx, sbuf) * (1.f / D);
    float y = dx * rsqrtf(var + 1e-6f) * g1[tid] + b1[tid];
    h_o[bt * D + tid] = y * ((session[bt] != 0) ? 1.f : 0.f);
}

// ---------------- 6. FFN + LN2 + projection -> G(bf16), Fn2 ----------------
__global__ void k_ffn_G(const int* __restrict__ session,
                        const float* __restrict__ h,
                        const float* __restrict__ FF1, const float* __restrict__ FF2,
                        const float* __restrict__ g2, const float* __restrict__ b2,
                        const float* __restrict__ ps, const float* __restrict__ v,
                        short* __restrict__ G16, float* __restrict__ Fn2) {
    int bt = blockIdx.x; int b = bt / T; int tid = threadIdx.x;
    __shared__ __align__(16) float hr[D];
    __shared__ __align__(16) float t1[D];
    __shared__ float sbuf[2];
    float hx = h[bt * D + tid];
    hr[tid] = hx;
    __syncthreads();
    float a = 0.f;
    const float4* w14 = (const float4*)(FF1 + tid * D);
    const float4* h4 = (const float4*)hr;
    #pragma unroll 8
    for (int k = 0; k < D / 4; ++k) {
        float4 w = w14[k]; float4 hv = h4[k];
        a += hv.x * w.x + hv.y * w.y + hv.z * w.z + hv.w * w.w;
    }
    t1[tid] = fmaxf(a, 0.f);
    __syncthreads();
    float f = 0.f;
    const float4* w24 = (const float4*)(FF2 + tid * D);
    const float4* t4 = (const float4*)t1;
    #pragma unroll 8
    for (int k = 0; k < D / 4; ++k) {
        float4 w = w24[k]; float4 tv = t4[k];
        f += tv.x * w.x + tv.y * w.y + tv.z * w.z + tv.w * w.w;
    }
    float x = f + hx;
    float mean = blockReduceSum128(x, sbuf) * (1.f / D);
    float dx = x - mean;
    float var = blockReduceSum128(dx * dx, sbuf) * (1.f / D);
    float ss = dx * rsqrtf(var + 1e-6f) * g2[tid] + b2[tid];
    ss *= (session[bt] != 0) ? 1.f : 0.f;
    float vb = v[b * D + tid];
    float vs = blockReduceSum128(vb * ss, sbuf);
    float ssp = ss - vb * vs;                  // s_s_proj
    float Fd = ps[b * D + tid] + ssp;          // F
    float Fv = blockReduceSum128(Fd * vb, sbuf);
    float Gd = Fd - Fv * vb;                   // G = F - (F.v) v
    float fn2 = blockReduceSum128(Fd * Fd, sbuf);
    G16[bt * D + tid] = (short)f2bf(Gd);
    if (tid == 0) Fn2[bt] = fn2;
}

#define LDK 136   // 128 + 8 pad shorts -> 272B row stride, balanced bank groups on ds_read_b128

// ---------------- 7. big dist kernel: bf16 MFMA 64x64 tile, inline In2/vI, nt stores ----------------
// out[row,col] = Fn2[row] + ||I_col||^2 - (v_b . I_col)^2 - 2 * (G_row . I_col)
// In2 and v.I computed in fp32 during staging (each 64-row tile spans <=2 b values).
__global__ __launch_bounds__(256) void k_dist_mfma(const short* __restrict__ G16,
                                                   const float* __restrict__ I,
                                                   const float* __restrict__ v,
                                                   const float* __restrict__ Fn2,
                                                   float* __restrict__ out) {
    __shared__ __align__(16) short As[64][LDK];
    __shared__ __align__(16) short Bs[64][LDK];
    __shared__ float sq[64][4];
    __shared__ float vip0[64][4];
    __shared__ float vip1[64][4];
    __shared__ float A2[2][64];      // In2 - vI^2 per (bb, col)
    int bt0 = blockIdx.y * 64;
    int n0  = blockIdx.x * 64;
    int tid = threadIdx.x;
    int b0 = bt0 / T;
    int b1 = (bt0 + 63) / T;         // <= b0+1
    // A staging: G16 64 rows x 128 shorts
    {
        int r = tid >> 4;          // 0..15
        int c = (tid & 15) * 8;
        #pragma unroll
        for (int s = 0; s < 4; ++s) {
            int row = r + s * 16;
            *(short8v*)&As[row][c] = *(const short8v*)&G16[(size_t)(bt0 + row) * D + c];
        }
    }
    // B staging: I 64 rows x 128 fp32 -> bf16, with fp32 partials for ||I||^2, v_b0.I, v_b1.I
    {
        int br = tid >> 2;
        int q  = tid & 3;
        int bq = q * 32;
        int n = n0 + br;
        float ss = 0.f, d0 = 0.f, d1 = 0.f;
        if (n < N1) {
            const float4* src = (const float4*)&I[(size_t)n * D + bq];
            const float4* v0  = (const float4*)&v[b0 * D + bq];
            const float4* v1  = (const float4*)&v[b1 * D + bq];
            #pragma unroll
            for (int s = 0; s < 8; ++s) {
                float4 f = src[s];
                float4 a = v0[s];
                float4 c = v1[s];
                ss += f.x * f.x + f.y * f.y + f.z * f.z + f.w * f.w;
                d0 += f.x * a.x + f.y * a.y + f.z * a.z + f.w * a.w;
                d1 += f.x * c.x + f.y * c.y + f.z * c.z + f.w * c.w;
                ushort4 u;
                u.x = f2bf(f.x); u.y = f2bf(f.y); u.z = f2bf(f.z); u.w = f2bf(f.w);
                *(ushort4*)&Bs[br][bq + s * 4] = u;
            }
        } else {
            #pragma unroll
            for (int s = 0; s < 8; ++s)
                *(ushort4*)&Bs[br][bq + s * 4] = make_ushort4(0, 0, 0, 0);
        }
        sq[br][q] = ss; vip0[br][q] = d0; vip1[br][q] = d1;
    }
    __syncthreads();
    int w  = tid >> 6;   // wave 0..3 -> A rows [w*16, w*16+16)
    int l  = tid & 63;
    int lr = l & 15;
    int lg = l >> 4;
    f32x4 acc[4] = {{0.f,0.f,0.f,0.f},{0.f,0.f,0.f,0.f},{0.f,0.f,0.f,0.f},{0.f,0.f,0.f,0.f}};
    short8v af[4];
    #pragma unroll
    for (int ks = 0; ks < 4; ++ks)
        af[ks] = *(const short8v*)&As[w * 16 + lr][ks * 32 + lg * 8];
    #pragma unroll
    for (int nt = 0; nt < 4; ++nt) {
        #pragma unroll
        for (int ks = 0; ks < 4; ++ks) {
            short8v bf = *(const short8v*)&Bs[nt * 16 + lr][ks * 32 + lg * 8];
            acc[nt] = __builtin_amdgcn_mfma_f32_16x16x32_bf16(af[ks], bf, acc[nt], 0, 0, 0);
        }
    }
    // combine partials -> A2[bb][col]
    if (tid < 64) {
        float in2 = sq[tid][0] + sq[tid][1] + sq[tid][2] + sq[tid][3];
        float vi0 = vip0[tid][0] + vip0[tid][1] + vip0[tid][2] + vip0[tid][3];
        float vi1 = vip1[tid][0] + vip1[tid][1] + vip1[tid][2] + vip1[tid][3];
        A2[0][tid] = in2 - vi0 * vi0;
        A2[1][tid] = in2 - vi1 * vi1;
    }
    __syncthreads();
    // epilogue: nontemporal stores (don't thrash L2/L3 so I stays resident)
    float4 fn4 = *(const float4*)&Fn2[bt0 + w * 16 + lg * 4];
    float fnv[4] = {fn4.x, fn4.y, fn4.z, fn4.w};
    #pragma unroll
    for (int nt = 0; nt < 4; ++nt) {
        int cl = nt * 16 + lr;
        int col = n0 + cl;
        if (col < N1) {
            float a0 = A2[0][cl];
            float a1 = A2[1][cl];
            #pragma unroll
            for (int i = 0; i < 4; ++i) {
                int row = bt0 + w * 16 + lg * 4 + i;
                int bb = (row / T) != b0;
                float val = fnv[i] + (bb ? a1 : a0) - 2.f * acc[nt][i];
                __builtin_nontemporal_store(val, &out[(size_t)row * N1 + col]);
            }
        }
    }
}

// ---------------- launch ----------------
extern "C" void kernel_launch(void* const* d_in, const int* in_sizes, int n_in,
                              void* d_out, int out_size, void* d_ws, size_t ws_size,
                              hipStream_t stream) {
    const int*   session = (const int*)d_in[0];
    const int*   lengths = (const int*)d_in[1];
    const int*   tau     = (const int*)d_in[2];
    const float* I_emb   = (const float*)d_in[5];
    const float* P_emb   = (const float*)d_in[6];
    const float* EP      = (const float*)d_in[7];
    const float* ES      = (const float*)d_in[8];
    const float* V       = (const float*)d_in[9];
    const float* WP1     = (const float*)d_in[10];
    const float* WP2     = (const float*)d_in[11];
    const float* Wq      = (const float*)d_in[12];
    const float* Wk      = (const float*)d_in[13];
    const float* Wv      = (const float*)d_in[14];
    const float* Wo      = (const float*)d_in[15];
    const float* FF1     = (const float*)d_in[16];
    const float* FF2     = (const float*)d_in[17];
    const float* g1      = (const float*)d_in[18];
    const float* b1      = (const float*)d_in[19];
    const float* g2      = (const float*)d_in[20];
    const float* b2      = (const float*)d_in[21];
    float* out = (float*)d_out;
    float* ws  = (float*)d_ws;

    // workspace layout (floats)
    float* wsX2   = ws;                       // 25600
    float* wsPs   = wsX2 + 25600;             // 4096
    float* wsV    = wsPs + 4096;              // 4096
    float* wsXs   = wsV + 4096;               // 204800 each, x6
    float* wsQ    = wsXs + 204800;
    float* wsK    = wsQ + 204800;
    float* wsVv   = wsK + 204800;
    float* wsHo   = wsVv + 204800;
    float* wsH    = wsHo + 204800;
    float* wsFn2  = wsH + 204800;             // 1600
    short* wsG16  = (short*)(wsFn2 + 1600);   // 204800 shorts

    float* orth_out = out + (size_t)BT * N1;

    k_proxy_x2 <<<BT, 128, 0, stream>>>(session, I_emb, EP, WP1, WP2, wsX2);
    k_proxy_head<<<B, 128, 0, stream>>>(wsX2, lengths, tau, P_emb, V, wsPs, wsV, orth_out);
    k_xs_qkv  <<<BT, 128, 0, stream>>>(session, lengths, I_emb, ES, Wq, Wk, Wv,
                                       wsXs, wsQ, wsK, wsVv);
    k_attn    <<<BT, 128, 0, stream>>>(session, wsQ, wsK, wsVv, wsHo);
    k_post_attn<<<BT, 128, 0, stream>>>(session, wsHo, Wo, wsXs, g1, b1, wsH);
    k_ffn_G   <<<BT, 128, 0, stream>>>(session, wsH, FF1, FF2, g2, b2, wsPs, wsV,
                                       wsG16, wsFn2);
    dim3 gdist((N1 + 63) / 64, BT / 64);
    k_dist_mfma<<<gdist, 256, 0, stream>>>(wsG16, I_emb, wsV, wsFn2, out);
}

// Round 6
// 387.572 us; speedup vs baseline: 1.0565x; 1.0565x over previous
//
#include <hip/hip_runtime.h>
#include <math.h>

#define B   32
#define T   50
#define N1  50001
#define D   128
#define KP  16
#define MP  50
#define HID 72
#define BT  (B*T)

typedef __attribute__((ext_vector_type(8))) short short8v;
typedef __attribute__((ext_vector_type(4))) float f32x4;

__device__ __forceinline__ unsigned short f2bf(float x) {
    unsigned u = __float_as_uint(x);
    u += 0x7fffu + ((u >> 16) & 1u);
    return (unsigned short)(u >> 16);
}

// ---------------- helpers ----------------
__device__ __forceinline__ float blockReduceSum128(float val, volatile float* sbuf) {
    // blockDim.x == 128 (2 waves of 64)
    for (int off = 32; off > 0; off >>= 1) val += __shfl_down(val, off, 64);
    __syncthreads();                       // protect sbuf from previous use
    if ((threadIdx.x & 63) == 0) sbuf[threadIdx.x >> 6] = val;
    __syncthreads();
    return sbuf[0] + sbuf[1];
}

// ---------------- 1. ProxySelection MLP per (b,t) ----------------
__global__ void k_proxy_x2(const int* __restrict__ session,
                           const float* __restrict__ I_emb,
                           const float* __restrict__ EP_emb,
                           const float* __restrict__ WP1,
                           const float* __restrict__ WP2,
                           float* __restrict__ X2) {
    int bt = blockIdx.x; int t = bt % T;
    int tid = threadIdx.x;                 // 128
    __shared__ __align__(16) float x[D];
    __shared__ float h[HID];
    int sid = session[bt];
    float val = 0.f;
    if (sid != 0) val = I_emb[(size_t)sid * D + tid] + EP_emb[(t + MP - T) * D + tid];
    x[tid] = val;
    __syncthreads();
    if (tid < HID) {
        float acc = 0.f;
        const float4* w4 = (const float4*)(WP1 + tid * D);
        const float4* x4 = (const float4*)x;
        #pragma unroll 8
        for (int k = 0; k < D / 4; ++k) {
            float4 w = w4[k]; float4 xv = x4[k];
            acc += xv.x * w.x + xv.y * w.y + xv.z * w.z + xv.w * w.w;
        }
        h[tid] = acc > 0.f ? acc : 0.1f * acc;   // leaky_relu 0.1
    }
    __syncthreads();
    if (tid < KP) {
        float acc = 0.f;
        const float* w = WP2 + tid * HID;
        for (int k = 0; k < HID; ++k) acc += h[k] * w[k];
        X2[bt * KP + tid] = acc;
    }
}

// ---------------- 2. softmax head: pi, p_s, v, orthogonal ----------------
__global__ void k_proxy_head(const float* __restrict__ X2,
                             const int* __restrict__ lengths,
                             const int* __restrict__ tau_i,
                             const float* __restrict__ P_emb,
                             const float* __restrict__ V,
                             float* __restrict__ ps_o,
                             float* __restrict__ v_o,
                             float* __restrict__ orth_o) {
    int b = blockIdx.x; int tid = threadIdx.x;   // 128
    __shared__ float pi[KP];
    __shared__ float vn[KP];
    __shared__ float sbuf[2];
    float tau = (float)tau_i[0];
    float lf = (float)lengths[b];
    if (tid < KP) {
        float s = 0.f;
        for (int t = 0; t < T; ++t) s += X2[(b * T + t) * KP + tid];
        pi[tid] = (s / lf) / tau;
    }
    if (tid < KP) {   // V row norms
        float s = 0.f;
        for (int d = 0; d < D; ++d) { float z = V[tid * D + d]; s += z * z; }
        vn[tid] = fmaxf(sqrtf(s), 1e-12f);
    }
    __syncthreads();
    if (tid == 0) {
        float m = pi[0];
        for (int k = 1; k < KP; ++k) m = fmaxf(m, pi[k]);
        float s = 0.f;
        for (int k = 0; k < KP; ++k) { float e = expf(pi[k] - m); pi[k] = e; s += e; }
        for (int k = 0; k < KP; ++k) pi[k] /= s;
    }
    __syncthreads();
    float p = 0.f, vt = 0.f;
    for (int k = 0; k < KP; ++k) {
        p  += pi[k] * P_emb[k * D + tid];
        vt += pi[k] * (V[k * D + tid] / vn[k]);
    }
    float vsq = blockReduceSum128(vt * vt, sbuf);
    float vv = vt / fmaxf(sqrtf(vsq), 1e-12f);
    float psq = blockReduceSum128(p * p, sbuf);
    float dvp = blockReduceSum128(vv * p, sbuf);
    ps_o[b * D + tid] = p;
    v_o[b * D + tid] = vv;
    if (tid == 0) orth_o[b] = fabsf(dvp) / sqrtf(psq);
}

// ---------------- 3. Xs, q, k, v ----------------
__global__ void k_xs_qkv(const int* __restrict__ session,
                         const int* __restrict__ lengths,
                         const float* __restrict__ I_emb,
                         const float* __restrict__ ES_emb,
                         const float* __restrict__ Wq,
                         const float* __restrict__ Wk,
                         const float* __restrict__ Wv,
                         float* __restrict__ xs_o, float* __restrict__ q_o,
                         float* __restrict__ k_o, float* __restrict__ v_o) {
    int bt = blockIdx.x; int b = bt / T; int t = bt % T;
    int tid = threadIdx.x;  // 128
    __shared__ __align__(16) float xs[D];
    int sid = session[bt];
    int es = t + 1 - (T - lengths[b]); if (es < 0) es = 0;
    float x = I_emb[(size_t)sid * D + tid] + ES_emb[es * D + tid];
    xs[tid] = x;
    __syncthreads();
    float aq = 0.f, ak = 0.f, av = 0.f;
    const float4* wq4 = (const float4*)(Wq + tid * D);
    const float4* wk4 = (const float4*)(Wk + tid * D);
    const float4* wv4 = (const float4*)(Wv + tid * D);
    const float4* x4  = (const float4*)xs;
    #pragma unroll 8
    for (int k = 0; k < D / 4; ++k) {
        float4 xv = x4[k];
        float4 a = wq4[k], bq = wk4[k], c = wv4[k];
        aq += xv.x * a.x + xv.y * a.y + xv.z * a.z + xv.w * a.w;
        ak += xv.x * bq.x + xv.y * bq.y + xv.z * bq.z + xv.w * bq.w;
        av += xv.x * c.x + xv.y * c.y + xv.z * c.z + xv.w * c.w;
    }
    xs_o[bt * D + tid] = x; q_o[bt * D + tid] = aq; k_o[bt * D + tid] = ak; v_o[bt * D + tid] = av;
}

// ---------------- 4. attention: scores + softmax + attn@vv ----------------
__global__ void k_attn(const int* __restrict__ session,
                       const float* __restrict__ q,
                       const float* __restrict__ kk,
                       const float* __restrict__ vv,
                       float* __restrict__ ho) {
    int bt = blockIdx.x; int b = bt / T; int t = bt % T;
    int tid = threadIdx.x;  // 128
    __shared__ __align__(16) float qs[D];
    __shared__ float attn[64];
    qs[tid] = q[bt * D + tid];
    __syncthreads();
    if (tid < T) {
        int s = tid;
        bool allowed = (s == 0) || ((s <= t) && (session[b * T + s] != 0));
        float sc = -1e9f;
        if (allowed) {
            float a = 0.f;
            const float4* kr = (const float4*)(kk + (size_t)(b * T + s) * D);
            const float4* q4 = (const float4*)qs;
            #pragma unroll 8
            for (int d = 0; d < D / 4; ++d) {
                float4 kv = kr[d]; float4 qv = q4[d];
                a += qv.x * kv.x + qv.y * kv.y + qv.z * kv.z + qv.w * kv.w;
            }
            sc = a * 0.088388347648318447f;  // 1/sqrt(128)
        }
        attn[s] = sc;
    }
    __syncthreads();
    if (tid < 64) {
        float vsc = (tid < T) ? attn[tid] : -1e30f;
        float m = vsc;
        for (int off = 32; off > 0; off >>= 1) m = fmaxf(m, __shfl_xor(m, off, 64));
        float e = (tid < T) ? expf(vsc - m) : 0.f;
        float ssum = e;
        for (int off = 32; off > 0; off >>= 1) ssum += __shfl_xor(ssum, off, 64);
        if (tid < T) attn[tid] = e / ssum;
    }
    __syncthreads();
    float acc = 0.f;
    for (int s = 0; s < T; ++s) acc += attn[s] * vv[(size_t)(b * T + s) * D + tid];
    ho[bt * D + tid] = acc;
}

// ---------------- 5. Wo + residual + LN1 ----------------
__global__ void k_post_attn(const int* __restrict__ session,
                            const float* __restrict__ ho,
                            const float* __restrict__ Wo,
                            const float* __restrict__ xs,
                            const float* __restrict__ g1, const float* __restrict__ b1,
                            float* __restrict__ h_o) {
    int bt = blockIdx.x; int tid = threadIdx.x;
    __shared__ __align__(16) float hr[D];
    __shared__ float sbuf[2];
    hr[tid] = ho[bt * D + tid];
    __syncthreads();
    float a = 0.f;
    const float4* w4 = (const float4*)(Wo + tid * D);
    const float4* h4 = (const float4*)hr;
    #pragma unroll 8
    for (int k = 0; k < D / 4; ++k) {
        float4 w = w4[k]; float4 hv = h4[k];
        a += hv.x * w.x + hv.y * w.y + hv.z * w.z + hv.w * w.w;
    }
    float x = a + xs[bt * D + tid];
    float mean = blockReduceSum128(x, sbuf) * (1.f / D);
    float dx = x - mean;
    float var = blockReduceSum128(dx * dx, sbuf) * (1.f / D);
    float y = dx * rsqrtf(var + 1e-6f) * g1[tid] + b1[tid];
    h_o[bt * D + tid] = y * ((session[bt] != 0) ? 1.f : 0.f);
}

// ---------------- 6. FFN + LN2 + projection -> G(bf16), Fn2 ----------------
__global__ void k_ffn_G(const int* __restrict__ session,
                        const float* __restrict__ h,
                        const float* __restrict__ FF1, const float* __restrict__ FF2,
                        const float* __restrict__ g2, const float* __restrict__ b2,
                        const float* __restrict__ ps, const float* __restrict__ v,
                        short* __restrict__ G16, float* __restrict__ Fn2) {
    int bt = blockIdx.x; int b = bt / T; int tid = threadIdx.x;
    __shared__ __align__(16) float hr[D];
    __shared__ __align__(16) float t1[D];
    __shared__ float sbuf[2];
    float hx = h[bt * D + tid];
    hr[tid] = hx;
    __syncthreads();
    float a = 0.f;
    const float4* w14 = (const float4*)(FF1 + tid * D);
    const float4* h4 = (const float4*)hr;
    #pragma unroll 8
    for (int k = 0; k < D / 4; ++k) {
        float4 w = w14[k]; float4 hv = h4[k];
        a += hv.x * w.x + hv.y * w.y + hv.z * w.z + hv.w * w.w;
    }
    t1[tid] = fmaxf(a, 0.f);
    __syncthreads();
    float f = 0.f;
    const float4* w24 = (const float4*)(FF2 + tid * D);
    const float4* t4 = (const float4*)t1;
    #pragma unroll 8
    for (int k = 0; k < D / 4; ++k) {
        float4 w = w24[k]; float4 tv = t4[k];
        f += tv.x * w.x + tv.y * w.y + tv.z * w.z + tv.w * w.w;
    }
    float x = f + hx;
    float mean = blockReduceSum128(x, sbuf) * (1.f / D);
    float dx = x - mean;
    float var = blockReduceSum128(dx * dx, sbuf) * (1.f / D);
    float ss = dx * rsqrtf(var + 1e-6f) * g2[tid] + b2[tid];
    ss *= (session[bt] != 0) ? 1.f : 0.f;
    float vb = v[b * D + tid];
    float vs = blockReduceSum128(vb * ss, sbuf);
    float ssp = ss - vb * vs;                  // s_s_proj
    float Fd = ps[b * D + tid] + ssp;          // F
    float Fv = blockReduceSum128(Fd * vb, sbuf);
    float Gd = Fd - Fv * vb;                   // G = F - (F.v) v
    float fn2 = blockReduceSum128(Fd * Fd, sbuf);
    G16[bt * D + tid] = (short)f2bf(Gd);
    if (tid == 0) Fn2[bt] = fn2;
}

#define LDK 136   // 128 + 8 pad shorts -> 272B row stride, balanced bank groups on ds_read_b128

// ---------------- 7. big dist kernel: bf16 MFMA 64x64 tile, inline In2/vI ----------------
// Grid: x = row-tile (25, fastest-varying) so the in-flight block window covers ALL row
// tiles of a narrow column range -> each I column tile is fetched once and consumed hot.
// out[row,col] = Fn2[row] + ||I_col||^2 - (v_b . I_col)^2 - 2 * (G_row . I_col)
__global__ __launch_bounds__(256) void k_dist_mfma(const short* __restrict__ G16,
                                                   const float* __restrict__ I,
                                                   const float* __restrict__ v,
                                                   const float* __restrict__ Fn2,
                                                   float* __restrict__ out) {
    __shared__ __align__(16) short As[64][LDK];
    __shared__ __align__(16) short Bs[64][LDK];
    __shared__ float sq[64][4];
    __shared__ float vip0[64][4];
    __shared__ float vip1[64][4];
    __shared__ float A2[2][64];      // In2 - vI^2 per (bb, col)
    int bt0 = blockIdx.x * 64;       // row tile (25) — fastest varying
    int n0  = blockIdx.y * 64;       // col tile (782)
    int tid = threadIdx.x;
    int b0 = bt0 / T;
    int b1 = (bt0 + 63) / T;         // <= b0+1
    // A staging: G16 64 rows x 128 shorts
    {
        int r = tid >> 4;          // 0..15
        int c = (tid & 15) * 8;
        #pragma unroll
        for (int s = 0; s < 4; ++s) {
            int row = r + s * 16;
            *(short8v*)&As[row][c] = *(const short8v*)&G16[(size_t)(bt0 + row) * D + c];
        }
    }
    // B staging: I 64 rows x 128 fp32 -> bf16, with fp32 partials for ||I||^2, v_b0.I, v_b1.I
    {
        int br = tid >> 2;
        int q  = tid & 3;
        int bq = q * 32;
        int n = n0 + br;
        float ss = 0.f, d0 = 0.f, d1 = 0.f;
        if (n < N1) {
            const float4* src = (const float4*)&I[(size_t)n * D + bq];
            const float4* v0  = (const float4*)&v[b0 * D + bq];
            const float4* v1  = (const float4*)&v[b1 * D + bq];
            #pragma unroll
            for (int s = 0; s < 8; ++s) {
                float4 f = src[s];
                float4 a = v0[s];
                float4 c = v1[s];
                ss += f.x * f.x + f.y * f.y + f.z * f.z + f.w * f.w;
                d0 += f.x * a.x + f.y * a.y + f.z * a.z + f.w * a.w;
                d1 += f.x * c.x + f.y * c.y + f.z * c.z + f.w * c.w;
                ushort4 u;
                u.x = f2bf(f.x); u.y = f2bf(f.y); u.z = f2bf(f.z); u.w = f2bf(f.w);
                *(ushort4*)&Bs[br][bq + s * 4] = u;
            }
        } else {
            #pragma unroll
            for (int s = 0; s < 8; ++s)
                *(ushort4*)&Bs[br][bq + s * 4] = make_ushort4(0, 0, 0, 0);
        }
        sq[br][q] = ss; vip0[br][q] = d0; vip1[br][q] = d1;
    }
    __syncthreads();
    int w  = tid >> 6;   // wave 0..3 -> A rows [w*16, w*16+16)
    int l  = tid & 63;
    int lr = l & 15;
    int lg = l >> 4;
    f32x4 acc[4] = {{0.f,0.f,0.f,0.f},{0.f,0.f,0.f,0.f},{0.f,0.f,0.f,0.f},{0.f,0.f,0.f,0.f}};
    short8v af[4];
    #pragma unroll
    for (int ks = 0; ks < 4; ++ks)
        af[ks] = *(const short8v*)&As[w * 16 + lr][ks * 32 + lg * 8];
    #pragma unroll
    for (int nt = 0; nt < 4; ++nt) {
        #pragma unroll
        for (int ks = 0; ks < 4; ++ks) {
            short8v bf = *(const short8v*)&Bs[nt * 16 + lr][ks * 32 + lg * 8];
            acc[nt] = __builtin_amdgcn_mfma_f32_16x16x32_bf16(af[ks], bf, acc[nt], 0, 0, 0);
        }
    }
    // combine partials -> A2[bb][col]
    if (tid < 64) {
        float in2 = sq[tid][0] + sq[tid][1] + sq[tid][2] + sq[tid][3];
        float vi0 = vip0[tid][0] + vip0[tid][1] + vip0[tid][2] + vip0[tid][3];
        float vi1 = vip1[tid][0] + vip1[tid][1] + vip1[tid][2] + vip1[tid][3];
        A2[0][tid] = in2 - vi0 * vi0;
        A2[1][tid] = in2 - vi1 * vi1;
    }
    __syncthreads();
    // epilogue: normal (cache-backed) stores so L2 merges straddling 64B segments
    float4 fn4 = *(const float4*)&Fn2[bt0 + w * 16 + lg * 4];
    float fnv[4] = {fn4.x, fn4.y, fn4.z, fn4.w};
    #pragma unroll
    for (int nt = 0; nt < 4; ++nt) {
        int cl = nt * 16 + lr;
        int col = n0 + cl;
        if (col < N1) {
            float a0 = A2[0][cl];
            float a1 = A2[1][cl];
            #pragma unroll
            for (int i = 0; i < 4; ++i) {
                int row = bt0 + w * 16 + lg * 4 + i;
                int bb = (row / T) != b0;
                out[(size_t)row * N1 + col] = fnv[i] + (bb ? a1 : a0) - 2.f * acc[nt][i];
            }
        }
    }
}

// ---------------- launch ----------------
extern "C" void kernel_launch(void* const* d_in, const int* in_sizes, int n_in,
                              void* d_out, int out_size, void* d_ws, size_t ws_size,
                              hipStream_t stream) {
    const int*   session = (const int*)d_in[0];
    const int*   lengths = (const int*)d_in[1];
    const int*   tau     = (const int*)d_in[2];
    const float* I_emb   = (const float*)d_in[5];
    const float* P_emb   = (const float*)d_in[6];
    const float* EP      = (const float*)d_in[7];
    const float* ES      = (const float*)d_in[8];
    const float* V       = (const float*)d_in[9];
    const float* WP1     = (const float*)d_in[10];
    const float* WP2     = (const float*)d_in[11];
    const float* Wq      = (const float*)d_in[12];
    const float* Wk      = (const float*)d_in[13];
    const float* Wv      = (const float*)d_in[14];
    const float* Wo      = (const float*)d_in[15];
    const float* FF1     = (const float*)d_in[16];
    const float* FF2     = (const float*)d_in[17];
    const float* g1      = (const float*)d_in[18];
    const float* b1      = (const float*)d_in[19];
    const float* g2      = (const float*)d_in[20];
    const float* b2      = (const float*)d_in[21];
    float* out = (float*)d_out;
    float* ws  = (float*)d_ws;

    // workspace layout (floats)
    float* wsX2   = ws;                       // 25600
    float* wsPs   = wsX2 + 25600;             // 4096
    float* wsV    = wsPs + 4096;              // 4096
    float* wsXs   = wsV + 4096;               // 204800 each, x6
    float* wsQ    = wsXs + 204800;
    float* wsK    = wsQ + 204800;
    float* wsVv   = wsK + 204800;
    float* wsHo   = wsVv + 204800;
    float* wsH    = wsHo + 204800;
    float* wsFn2  = wsH + 204800;             // 1600
    short* wsG16  = (short*)(wsFn2 + 1600);   // 204800 shorts

    float* orth_out = out + (size_t)BT * N1;

    k_proxy_x2 <<<BT, 128, 0, stream>>>(session, I_emb, EP, WP1, WP2, wsX2);
    k_proxy_head<<<B, 128, 0, stream>>>(wsX2, lengths, tau, P_emb, V, wsPs, wsV, orth_out);
    k_xs_qkv  <<<BT, 128, 0, stream>>>(session, lengths, I_emb, ES, Wq, Wk, Wv,
                                       wsXs, wsQ, wsK, wsVv);
    k_attn    <<<BT, 128, 0, stream>>>(session, wsQ, wsK, wsVv, wsHo);
    k_post_attn<<<BT, 128, 0, stream>>>(session, wsHo, Wo, wsXs, g1, b1, wsH);
    k_ffn_G   <<<BT, 128, 0, stream>>>(session, wsH, FF1, FF2, g2, b2, wsPs, wsV,
                                       wsG16, wsFn2);
    dim3 gdist(BT / 64, (N1 + 63) / 64);
    k_dist_mfma<<<gdist, 256, 0, stream>>>(wsG16, I_emb, wsV, wsFn2, out);
}

// Round 7
// 308.489 us; speedup vs baseline: 1.3274x; 1.2564x over previous
//
#include <hip/hip_runtime.h>
#include <math.h>

#define B   32
#define T   50
#define N1  50001
#define D   128
#define KP  16
#define MP  50
#define HID 72
#define BT  (B*T)

typedef __attribute__((ext_vector_type(8))) short short8v;
typedef __attribute__((ext_vector_type(4))) float f32x4;

__device__ __forceinline__ unsigned short f2bf(float x) {
    unsigned u = __float_as_uint(x);
    u += 0x7fffu + ((u >> 16) & 1u);
    return (unsigned short)(u >> 16);
}

// ---------------- helpers ----------------
__device__ __forceinline__ float blockReduceSum128(float val, volatile float* sbuf) {
    // blockDim.x == 128 (2 waves of 64)
    for (int off = 32; off > 0; off >>= 1) val += __shfl_down(val, off, 64);
    __syncthreads();
    if ((threadIdx.x & 63) == 0) sbuf[threadIdx.x >> 6] = val;
    __syncthreads();
    return sbuf[0] + sbuf[1];
}

// ---------------- 1. fused: ProxySelection X2 + Xs/q/k/v ----------------
__global__ void k_fused_emb(const int* __restrict__ session,
                            const int* __restrict__ lengths,
                            const float* __restrict__ I_emb,
                            const float* __restrict__ EP_emb,
                            const float* __restrict__ ES_emb,
                            const float* __restrict__ WP1,
                            const float* __restrict__ WP2,
                            const float* __restrict__ Wq,
                            const float* __restrict__ Wk,
                            const float* __restrict__ Wv,
                            float* __restrict__ X2,
                            float* __restrict__ xs_o, float* __restrict__ q_o,
                            float* __restrict__ k_o, float* __restrict__ v_o) {
    int bt = blockIdx.x; int b = bt / T; int t = bt % T;
    int tid = threadIdx.x;   // 128
    __shared__ __align__(16) float x[D];
    __shared__ __align__(16) float xs[D];
    __shared__ float h[HID];
    int sid = session[bt];
    float ie = I_emb[(size_t)sid * D + tid];
    float xv_ = (sid != 0) ? (ie + EP_emb[(t + MP - T) * D + tid]) : 0.f;
    int es = t + 1 - (T - lengths[b]); if (es < 0) es = 0;
    float xsv = ie + ES_emb[es * D + tid];
    x[tid] = xv_;
    xs[tid] = xsv;
    __syncthreads();
    // q/k/v matvecs (all threads)
    float aq = 0.f, ak = 0.f, av = 0.f;
    {
        const float4* wq4 = (const float4*)(Wq + tid * D);
        const float4* wk4 = (const float4*)(Wk + tid * D);
        const float4* wv4 = (const float4*)(Wv + tid * D);
        const float4* x4  = (const float4*)xs;
        #pragma unroll 8
        for (int k = 0; k < D / 4; ++k) {
            float4 xv = x4[k];
            float4 a = wq4[k], bq = wk4[k], c = wv4[k];
            aq += xv.x * a.x + xv.y * a.y + xv.z * a.z + xv.w * a.w;
            ak += xv.x * bq.x + xv.y * bq.y + xv.z * bq.z + xv.w * bq.w;
            av += xv.x * c.x + xv.y * c.y + xv.z * c.z + xv.w * c.w;
        }
    }
    // WP1 (tid < HID)
    if (tid < HID) {
        float acc = 0.f;
        const float4* w4 = (const float4*)(WP1 + tid * D);
        const float4* x4 = (const float4*)x;
        #pragma unroll 8
        for (int k = 0; k < D / 4; ++k) {
            float4 w = w4[k]; float4 xv = x4[k];
            acc += xv.x * w.x + xv.y * w.y + xv.z * w.z + xv.w * w.w;
        }
        h[tid] = acc > 0.f ? acc : 0.1f * acc;
    }
    xs_o[bt * D + tid] = xsv;
    q_o[bt * D + tid] = aq; k_o[bt * D + tid] = ak; v_o[bt * D + tid] = av;
    __syncthreads();
    if (tid < KP) {
        float acc = 0.f;
        const float* w = WP2 + tid * HID;
        for (int k = 0; k < HID; ++k) acc += h[k] * w[k];
        X2[bt * KP + tid] = acc;
    }
}

// ---------------- 2. softmax head: pi, p_s, v, orthogonal ----------------
__global__ void k_proxy_head(const float* __restrict__ X2,
                             const int* __restrict__ lengths,
                             const int* __restrict__ tau_i,
                             const float* __restrict__ P_emb,
                             const float* __restrict__ V,
                             float* __restrict__ ps_o,
                             float* __restrict__ v_o,
                             float* __restrict__ orth_o) {
    int b = blockIdx.x; int tid = threadIdx.x;   // 128
    __shared__ float pi[KP];
    __shared__ float vn[KP];
    __shared__ float sbuf[2];
    float tau = (float)tau_i[0];
    float lf = (float)lengths[b];
    if (tid < KP) {
        float s = 0.f;
        for (int t = 0; t < T; ++t) s += X2[(b * T + t) * KP + tid];
        pi[tid] = (s / lf) / tau;
    }
    if (tid < KP) {
        float s = 0.f;
        for (int d = 0; d < D; ++d) { float z = V[tid * D + d]; s += z * z; }
        vn[tid] = fmaxf(sqrtf(s), 1e-12f);
    }
    __syncthreads();
    if (tid == 0) {
        float m = pi[0];
        for (int k = 1; k < KP; ++k) m = fmaxf(m, pi[k]);
        float s = 0.f;
        for (int k = 0; k < KP; ++k) { float e = expf(pi[k] - m); pi[k] = e; s += e; }
        for (int k = 0; k < KP; ++k) pi[k] /= s;
    }
    __syncthreads();
    float p = 0.f, vt = 0.f;
    for (int k = 0; k < KP; ++k) {
        p  += pi[k] * P_emb[k * D + tid];
        vt += pi[k] * (V[k * D + tid] / vn[k]);
    }
    float vsq = blockReduceSum128(vt * vt, sbuf);
    float vv = vt / fmaxf(sqrtf(vsq), 1e-12f);
    float psq = blockReduceSum128(p * p, sbuf);
    float dvp = blockReduceSum128(vv * p, sbuf);
    ps_o[b * D + tid] = p;
    v_o[b * D + tid] = vv;
    if (tid == 0) orth_o[b] = fabsf(dvp) / sqrtf(psq);
}

// ---------------- 3. fused: attention + Wo/LN1 + FFN/LN2 + projection -> G16, Fn2 ----------------
__global__ void k_fused_attn(const int* __restrict__ session,
                             const float* __restrict__ q,
                             const float* __restrict__ kk,
                             const float* __restrict__ vv,
                             const float* __restrict__ xs,
                             const float* __restrict__ Wo,
                             const float* __restrict__ g1, const float* __restrict__ b1,
                             const float* __restrict__ FF1, const float* __restrict__ FF2,
                             const float* __restrict__ g2, const float* __restrict__ b2,
                             const float* __restrict__ ps, const float* __restrict__ v,
                             short* __restrict__ G16, float* __restrict__ Fn2) {
    int bt = blockIdx.x; int b = bt / T; int t = bt % T;
    int tid = threadIdx.x;  // 128
    __shared__ __align__(16) float qs[D];
    __shared__ __align__(16) float buf1[D];
    __shared__ __align__(16) float buf2[D];
    __shared__ float attn[64];
    __shared__ float sbuf[2];
    // --- attention ---
    qs[tid] = q[bt * D + tid];
    __syncthreads();
    if (tid < T) {
        int s = tid;
        bool allowed = (s == 0) || ((s <= t) && (session[b * T + s] != 0));
        float sc = -1e9f;
        if (allowed) {
            float a = 0.f;
            const float4* kr = (const float4*)(kk + (size_t)(b * T + s) * D);
            const float4* q4 = (const float4*)qs;
            #pragma unroll 8
            for (int d = 0; d < D / 4; ++d) {
                float4 kv = kr[d]; float4 qv = q4[d];
                a += qv.x * kv.x + qv.y * kv.y + qv.z * kv.z + qv.w * kv.w;
            }
            sc = a * 0.088388347648318447f;  // 1/sqrt(128)
        }
        attn[s] = sc;
    }
    __syncthreads();
    if (tid < 64) {
        float vsc = (tid < T) ? attn[tid] : -1e30f;
        float m = vsc;
        for (int off = 32; off > 0; off >>= 1) m = fmaxf(m, __shfl_xor(m, off, 64));
        float e = (tid < T) ? expf(vsc - m) : 0.f;
        float ssum = e;
        for (int off = 32; off > 0; off >>= 1) ssum += __shfl_xor(ssum, off, 64);
        if (tid < T) attn[tid] = e / ssum;
    }
    __syncthreads();
    float acc = 0.f;
    for (int s = 0; s < T; ++s) acc += attn[s] * vv[(size_t)(b * T + s) * D + tid];
    // --- Wo + residual + LN1 ---
    buf1[tid] = acc;
    __syncthreads();
    float a = 0.f;
    {
        const float4* w4 = (const float4*)(Wo + tid * D);
        const float4* h4 = (const float4*)buf1;
        #pragma unroll 8
        for (int k = 0; k < D / 4; ++k) {
            float4 w = w4[k]; float4 hv = h4[k];
            a += hv.x * w.x + hv.y * w.y + hv.z * w.z + hv.w * w.w;
        }
    }
    float x1 = a + xs[bt * D + tid];
    float mean = blockReduceSum128(x1, sbuf) * (1.f / D);
    float dx = x1 - mean;
    float var = blockReduceSum128(dx * dx, sbuf) * (1.f / D);
    float hx = (dx * rsqrtf(var + 1e-6f) * g1[tid] + b1[tid]) * ((session[bt] != 0) ? 1.f : 0.f);
    // --- FFN + LN2 ---
    buf2[tid] = hx;
    __syncthreads();
    float a1 = 0.f;
    {
        const float4* w4 = (const float4*)(FF1 + tid * D);
        const float4* h4 = (const float4*)buf2;
        #pragma unroll 8
        for (int k = 0; k < D / 4; ++k) {
            float4 w = w4[k]; float4 hv = h4[k];
            a1 += hv.x * w.x + hv.y * w.y + hv.z * w.z + hv.w * w.w;
        }
    }
    __syncthreads();                 // all reads of buf1 (Wo) done long ago; reuse
    buf1[tid] = fmaxf(a1, 0.f);
    __syncthreads();
    float f = 0.f;
    {
        const float4* w4 = (const float4*)(FF2 + tid * D);
        const float4* t4 = (const float4*)buf1;
        #pragma unroll 8
        for (int k = 0; k < D / 4; ++k) {
            float4 w = w4[k]; float4 tv = t4[k];
            f += tv.x * w.x + tv.y * w.y + tv.z * w.z + tv.w * w.w;
        }
    }
    float x2 = f + hx;
    float mean2 = blockReduceSum128(x2, sbuf) * (1.f / D);
    float dx2 = x2 - mean2;
    float var2 = blockReduceSum128(dx2 * dx2, sbuf) * (1.f / D);
    float ss = dx2 * rsqrtf(var2 + 1e-6f) * g2[tid] + b2[tid];
    ss *= (session[bt] != 0) ? 1.f : 0.f;
    // --- projection -> G, Fn2 ---
    float vb = v[b * D + tid];
    float vs = blockReduceSum128(vb * ss, sbuf);
    float ssp = ss - vb * vs;
    float Fd = ps[b * D + tid] + ssp;
    float Fv = blockReduceSum128(Fd * vb, sbuf);
    float Gd = Fd - Fv * vb;
    float fn2 = blockReduceSum128(Fd * Fd, sbuf);
    G16[bt * D + tid] = (short)f2bf(Gd);
    if (tid == 0) Fn2[bt] = fn2;
}

#define LDK 136   // 128 + 8 pad shorts -> 272B row stride, balanced bank groups on ds_read_b128

// ---------------- 4. per-item stats via MFMA + I->bf16 spill ----------------
// In2pb[b,n] = ||I_n||^2 - (v_b . I_n)^2 ; also writes I16 (bf16 copy of I) for k_dist.
__global__ __launch_bounds__(256) void k_item_mfma(const float* __restrict__ I,
                                                   const float* __restrict__ v,
                                                   float* __restrict__ In2pb,
                                                   unsigned short* __restrict__ I16) {
    __shared__ __align__(16) short Is[64][LDK];
    __shared__ __align__(16) short Vs[32][LDK];
    __shared__ float sq[64][4];
    __shared__ float in2[64];
    int n0 = blockIdx.x * 64;
    int tid = threadIdx.x;   // 256
    {
        int vr = tid >> 3;
        int vc = (tid & 7) * 16;
        const float4* src = (const float4*)&v[vr * D + vc];
        #pragma unroll
        for (int s = 0; s < 4; ++s) {
            float4 f = src[s];
            ushort4 u;
            u.x = f2bf(f.x); u.y = f2bf(f.y); u.z = f2bf(f.z); u.w = f2bf(f.w);
            *(ushort4*)&Vs[vr][vc + s * 4] = u;
        }
    }
    {
        int r = tid >> 2;
        int qq = tid & 3;
        int n = n0 + r;
        float ss = 0.f;
        if (n < N1) {
            const float4* src = (const float4*)&I[(size_t)n * D + qq * 32];
            #pragma unroll
            for (int s = 0; s < 8; ++s) {
                float4 f = src[s];
                ss += f.x * f.x + f.y * f.y + f.z * f.z + f.w * f.w;
                ushort4 u;
                u.x = f2bf(f.x); u.y = f2bf(f.y); u.z = f2bf(f.z); u.w = f2bf(f.w);
                *(ushort4*)&Is[r][qq * 32 + s * 4] = u;
                *(ushort4*)&I16[(size_t)n * D + qq * 32 + s * 4] = u;
            }
        } else {
            #pragma unroll
            for (int s = 0; s < 8; ++s)
                *(ushort4*)&Is[r][qq * 32 + s * 4] = make_ushort4(0, 0, 0, 0);
        }
        sq[r][qq] = ss;
    }
    __syncthreads();
    if (tid < 64) in2[tid] = sq[tid][0] + sq[tid][1] + sq[tid][2] + sq[tid][3];
    __syncthreads();
    int w = tid >> 6, l = tid & 63, lr = l & 15, lg = l >> 4;
    f32x4 acc[2] = {{0.f,0.f,0.f,0.f},{0.f,0.f,0.f,0.f}};
    short8v af[4];
    #pragma unroll
    for (int ks = 0; ks < 4; ++ks)
        af[ks] = *(const short8v*)&Is[w * 16 + lr][ks * 32 + lg * 8];
    #pragma unroll
    for (int nt = 0; nt < 2; ++nt) {
        #pragma unroll
        for (int ks = 0; ks < 4; ++ks) {
            short8v bf = *(const short8v*)&Vs[nt * 16 + lr][ks * 32 + lg * 8];
            acc[nt] = __builtin_amdgcn_mfma_f32_16x16x32_bf16(af[ks], bf, acc[nt], 0, 0, 0);
        }
    }
    #pragma unroll
    for (int nt = 0; nt < 2; ++nt) {
        int b = nt * 16 + lr;
        #pragma unroll
        for (int i = 0; i < 4; ++i) {
            int item = w * 16 + lg * 4 + i;
            int n = n0 + item;
            if (n < N1) {
                float dvi = acc[nt][i];
                In2pb[(size_t)b * N1 + n] = in2[item] - dvi * dvi;
            }
        }
    }
}

// ---------------- 5. big dist kernel: 128x64 tile, bf16 MFMA, col-fastest grid ----------------
// out[row,col] = Fn2[row] + In2pb[b][col] - 2 * (G_row . I_col)
__global__ __launch_bounds__(256) void k_dist_mfma(const short* __restrict__ G16,
                                                   const unsigned short* __restrict__ I16,
                                                   const float* __restrict__ Fn2,
                                                   const float* __restrict__ In2pb,
                                                   float* __restrict__ out) {
    __shared__ __align__(16) short As[128][LDK];
    __shared__ __align__(16) short Bs[64][LDK];
    int n0  = blockIdx.x * 64;       // col tile (fastest) -> write locality
    int bt0 = blockIdx.y * 128;      // row tile (13, last partial)
    int tid = threadIdx.x;
    int r = tid >> 4;                // 0..15
    int c = (tid & 15) * 8;
    // A staging: G16, 128 rows
    #pragma unroll
    for (int s = 0; s < 8; ++s) {
        int row = r + s * 16;
        short8v gv = {};
        if (bt0 + row < BT) gv = *(const short8v*)&G16[(size_t)(bt0 + row) * D + c];
        *(short8v*)&As[row][c] = gv;
    }
    // B staging: I16, 64 rows
    #pragma unroll
    for (int s = 0; s < 4; ++s) {
        int row = r + s * 16;
        int n = n0 + row;
        short8v bv = {};
        if (n < N1) bv = *(const short8v*)&I16[(size_t)n * D + c];
        *(short8v*)&Bs[row][c] = bv;
    }
    __syncthreads();
    int w  = tid >> 6;   // wave 0..3 -> A rows [w*32, w*32+32)
    int l  = tid & 63;
    int lr = l & 15;
    int lg = l >> 4;
    short8v af[2][4];
    #pragma unroll
    for (int mi = 0; mi < 2; ++mi)
        #pragma unroll
        for (int ks = 0; ks < 4; ++ks)
            af[mi][ks] = *(const short8v*)&As[w * 32 + mi * 16 + lr][ks * 32 + lg * 8];
    f32x4 acc[2][4];
    #pragma unroll
    for (int mi = 0; mi < 2; ++mi)
        #pragma unroll
        for (int nt = 0; nt < 4; ++nt) acc[mi][nt] = (f32x4){0.f, 0.f, 0.f, 0.f};
    #pragma unroll
    for (int nt = 0; nt < 4; ++nt) {
        short8v bf[4];
        #pragma unroll
        for (int ks = 0; ks < 4; ++ks)
            bf[ks] = *(const short8v*)&Bs[nt * 16 + lr][ks * 32 + lg * 8];
        #pragma unroll
        for (int mi = 0; mi < 2; ++mi)
            #pragma unroll
            for (int ks = 0; ks < 4; ++ks)
                acc[mi][nt] = __builtin_amdgcn_mfma_f32_16x16x32_bf16(af[mi][ks], bf[ks], acc[mi][nt], 0, 0, 0);
    }
    // epilogue
    #pragma unroll
    for (int mi = 0; mi < 2; ++mi) {
        int rb = bt0 + w * 32 + mi * 16 + lg * 4;
        if (rb < BT) {
            float4 fn4 = *(const float4*)&Fn2[rb];
            float fnv[4] = {fn4.x, fn4.y, fn4.z, fn4.w};
            #pragma unroll
            for (int i = 0; i < 4; ++i) {
                int row = rb + i;
                int b = row / T;
                const float* inrow = In2pb + (size_t)b * N1;
                float* orow = out + (size_t)row * N1;
                #pragma unroll
                for (int nt = 0; nt < 4; ++nt) {
                    int col = n0 + nt * 16 + lr;
                    if (col < N1) orow[col] = fnv[i] + inrow[col] - 2.f * acc[mi][nt][i];
                }
            }
        }
    }
}

// ---------------- launch ----------------
extern "C" void kernel_launch(void* const* d_in, const int* in_sizes, int n_in,
                              void* d_out, int out_size, void* d_ws, size_t ws_size,
                              hipStream_t stream) {
    const int*   session = (const int*)d_in[0];
    const int*   lengths = (const int*)d_in[1];
    const int*   tau     = (const int*)d_in[2];
    const float* I_emb   = (const float*)d_in[5];
    const float* P_emb   = (const float*)d_in[6];
    const float* EP      = (const float*)d_in[7];
    const float* ES      = (const float*)d_in[8];
    const float* V       = (const float*)d_in[9];
    const float* WP1     = (const float*)d_in[10];
    const float* WP2     = (const float*)d_in[11];
    const float* Wq      = (const float*)d_in[12];
    const float* Wk      = (const float*)d_in[13];
    const float* Wv      = (const float*)d_in[14];
    const float* Wo      = (const float*)d_in[15];
    const float* FF1     = (const float*)d_in[16];
    const float* FF2     = (const float*)d_in[17];
    const float* g1      = (const float*)d_in[18];
    const float* b1      = (const float*)d_in[19];
    const float* g2      = (const float*)d_in[20];
    const float* b2      = (const float*)d_in[21];
    float* out = (float*)d_out;
    float* ws  = (float*)d_ws;

    // workspace layout (floats)
    float* wsX2   = ws;                       // 25600
    float* wsPs   = wsX2 + 25600;             // 4096
    float* wsV    = wsPs + 4096;              // 4096
    float* wsXs   = wsV + 4096;               // 204800 each
    float* wsQ    = wsXs + 204800;
    float* wsK    = wsQ + 204800;
    float* wsVv   = wsK + 204800;
    float* wsFn2  = wsVv + 204800;            // 1600
    float* wsIn2  = wsFn2 + 1600;             // 32*50001 = 1600032
    short* wsG16  = (short*)(wsIn2 + 1600032);            // 204800 shorts
    unsigned short* wsI16 = (unsigned short*)(wsG16 + 204800);  // 50001*128 shorts = 12.8 MB

    float* orth_out = out + (size_t)BT * N1;

    k_fused_emb <<<BT, 128, 0, stream>>>(session, lengths, I_emb, EP, ES,
                                         WP1, WP2, Wq, Wk, Wv,
                                         wsX2, wsXs, wsQ, wsK, wsVv);
    k_proxy_head<<<B, 128, 0, stream>>>(wsX2, lengths, tau, P_emb, V, wsPs, wsV, orth_out);
    k_fused_attn<<<BT, 128, 0, stream>>>(session, wsQ, wsK, wsVv, wsXs,
                                         Wo, g1, b1, FF1, FF2, g2, b2,
                                         wsPs, wsV, wsG16, wsFn2);
    k_item_mfma <<<(N1 + 63) / 64, 256, 0, stream>>>(I_emb, wsV, wsIn2, wsI16);
    dim3 gdist((N1 + 63) / 64, (BT + 127) / 128);
    k_dist_mfma <<<gdist, 256, 0, stream>>>(wsG16, wsI16, wsFn2, wsIn2, out);
}